// Round 20
// baseline (262.172 us; speedup 1.0000x reference)
//
#include <hip/hip_runtime.h>
#include <stdint.h>

#define NN 4096
#define DD 64
#define HH 256
#define VV 8192
#define NVv ((size_t)NN*(size_t)VV)

typedef float f4 __attribute__((ext_vector_type(4)));
__device__ __forceinline__ void ntstore(f4* p, f4 v){ __builtin_nontemporal_store(v, p); }

// ---------------- threefry2x32 (exact JAX replication) ----------------
__device__ __forceinline__ uint32_t rotl32(uint32_t v, int r){ return (v<<r)|(v>>(32-r)); }
#define TF_ROUND(r) do { x0 += x1; x1 = rotl32(x1, r); x1 ^= x0; } while(0)
__device__ __forceinline__ void threefry2x32(uint32_t k0, uint32_t k1,
                                             uint32_t c0, uint32_t c1,
                                             uint32_t& o0, uint32_t& o1){
  uint32_t ks2 = k0 ^ k1 ^ 0x1BD11BDAu;
  uint32_t x0 = c0 + k0, x1 = c1 + k1;
  TF_ROUND(13); TF_ROUND(15); TF_ROUND(26); TF_ROUND(6);
  x0 += k1;  x1 += ks2 + 1u;
  TF_ROUND(17); TF_ROUND(29); TF_ROUND(16); TF_ROUND(24);
  x0 += ks2; x1 += k0 + 2u;
  TF_ROUND(13); TF_ROUND(15); TF_ROUND(26); TF_ROUND(6);
  x0 += k0;  x1 += k1 + 3u;
  TF_ROUND(17); TF_ROUND(29); TF_ROUND(16); TF_ROUND(24);
  x0 += k1;  x1 += ks2 + 4u;
  TF_ROUND(13); TF_ROUND(15); TF_ROUND(26); TF_ROUND(6);
  x0 += ks2; x1 += k0 + 5u;
  o0 = x0; o1 = x1;
}

// ---------------- K1: fused t = log_sigmoid(xcat@delta) + RNG/cumsum -------
__global__ __launch_bounds__(256) void k_pre(const float* __restrict__ xcat,
                                             const float* __restrict__ delta,
                                             const int* __restrict__ xdiv,
                                             const int* __restrict__ seedp,
                                             float* __restrict__ t,
                                             int* __restrict__ dv){
  __shared__ float xr[64*65];
  __shared__ float dl[64];
  __shared__ int   md[NN];
  __shared__ int   ps[256];
  int tid = threadIdx.x;
  if (blockIdx.x < 64) {
    int b = blockIdx.x;
    if (tid < 64) dl[tid] = delta[tid];
    const float4* src = (const float4*)(xcat + (size_t)b*4096);
    for (int i = tid; i < 1024; i += 256) {
      float4 v = src[i];
      int r = i >> 4, c = (i & 15)*4;
      float* p = &xr[r*65 + c];
      p[0]=v.x; p[1]=v.y; p[2]=v.z; p[3]=v.w;
    }
    __syncthreads();
    if (tid < 64) {
      float acc = 0.f;
      #pragma unroll 16
      for (int d = 0; d < 64; ++d) acc = fmaf(xr[tid*65 + d], dl[d], acc);
      t[b*64 + tid] = fminf(acc, 0.f) - log1pf(expf(-fabsf(acc)));
    }
    return;
  }
  // block 64: RNG + cumsum
  uint32_t seed = (uint32_t)seedp[0];
  uint32_t sk0, sk1;
  threefry2x32(0u, seed, 0u, 1u, sk0, sk1);    // foldlike split -> subkey
  for (int i = tid; i < NN; i += 256) {
    uint32_t o0, o1; threefry2x32(sk0, sk1, 0u, (uint32_t)i, o0, o1);
    uint32_t bits = o0 ^ o1;                   // partitionable 32-bit bits
    float u = __uint_as_float((bits>>9)|0x3f800000u) - 1.0f;
    md[i] = (u > 0.1f) ? xdiv[i] : 0;
  }
  __syncthreads();
  int base = tid*16, s = 0;
  #pragma unroll
  for (int k=0;k<16;k++){ s += md[base+k]; md[base+k] = s; }
  ps[tid] = s;
  __syncthreads();
  if (tid < 64) {                              // wave-parallel exclusive scan
    int a0 = ps[4*tid], a1 = ps[4*tid+1], a2 = ps[4*tid+2], a3 = ps[4*tid+3];
    int s4 = a0+a1+a2+a3;
    int v = s4;
    #pragma unroll
    for (int o = 1; o < 64; o <<= 1) { int u = __shfl_up(v, o, 64); if (tid >= o) v += u; }
    int e = v - s4;
    ps[4*tid] = e; ps[4*tid+1] = e+a0; ps[4*tid+2] = e+a0+a1; ps[4*tid+3] = e+a0+a1+a2;
  }
  __syncthreads();
  int off = ps[tid];
  #pragma unroll
  for (int k=0;k<16;k++) dv[base+k] = md[base+k] + off;
}

// ---------------- wave-level combine (f-order): O = Y + m * (X*exp(dt*a)) @ B
__device__ __forceinline__ void wave_combine(const float* __restrict__ Xv,
                                             const float* __restrict__ Yv,
                                             float* __restrict__ Ov,
                                             int bidx, int cidx, int lane,
                                             const float* __restrict__ t,
                                             const int* __restrict__ sep,
                                             const int* __restrict__ dv,
                                             const float* __restrict__ al,
                                             const float* __restrict__ bl){
  int eb = (NN-1) - bidx, ec = (NN-1) - cidx;   // e-order indices
  float acc = Yv[lane];
  if (sep[eb] == sep[ec] && dv[eb] == dv[ec]) {
    float dt = t[ec] - t[eb];
    float w = Xv[lane] * expf(dt * al[lane]);
    #pragma unroll 16
    for (int d = 0; d < 64; ++d)
      acc = fmaf(__shfl(w, d, 64), bl[d*64 + lane], acc);
  }
  Ov[lane] = acc;
}

// ---------------- K2: subtree upsweep (levels 1..7) -> g7 ----------------
__global__ __launch_bounds__(1024) void k_up(const float* __restrict__ xcat,
    const float* __restrict__ t, const int* __restrict__ sep, const int* __restrict__ dv,
    const float* __restrict__ ap, const float* __restrict__ bp, float* __restrict__ g7){
  __shared__ float G[255*64];
  __shared__ float bl[64*64];
  __shared__ float al[64];
  int b = blockIdx.x, tid = threadIdx.x, lane = tid & 63, wv = tid >> 6;
  for (int i = tid; i < 4096; i += 1024) bl[i] = bp[i];
  if (tid < 64) al[tid] = ap[tid];
  for (int k = wv; k < 128; k += 16) G[k*64 + lane] = xcat[(NN-1 - (128*b + k))*DD + lane];
  __syncthreads();
  const int Gof[8] = {0,128,192,224,240,248,252,254};
  for (int L = 1; L <= 7; ++L) {
    int nc = 128 >> L, s = 1 << (L-1);
    for (int c = wv; c < nc; c += 16)
      wave_combine(&G[(Gof[L-1]+2*c)*64], &G[(Gof[L-1]+2*c+1)*64], &G[(Gof[L]+c)*64],
                   128*b + (2*c+1)*s - 1, 128*b + (2*c+2)*s - 1, lane, t, sep, dv, al, bl);
    __syncthreads();
  }
  if (tid < 64) g7[b*64 + tid] = G[254*64 + tid];
}

// ---------------- K3: middle levels 8..12 up + down -> scanned_7 ----------
__global__ __launch_bounds__(1024) void k_mid(const float* __restrict__ t,
    const int* __restrict__ sep, const int* __restrict__ dv,
    const float* __restrict__ ap, const float* __restrict__ bp,
    const float* __restrict__ g7, float* __restrict__ s7){
  __shared__ float G[63*64];
  __shared__ float R[63*64];
  __shared__ float bl[64*64];
  __shared__ float al[64];
  int tid = threadIdx.x, lane = tid & 63, wv = tid >> 6;
  for (int i = tid; i < 4096; i += 1024) bl[i] = bp[i];
  if (tid < 64) al[tid] = ap[tid];
  for (int k = wv; k < 32; k += 16) G[k*64 + lane] = g7[k*64 + lane];
  __syncthreads();
  const int Gof[13] = {0,0,0,0,0,0,0, 0,32,48,56,60,62};
  const int Rof[13] = {0,0,0,0,0,0,0, 31,15,7,3,1,0};
  for (int l = 8; l <= 12; ++l) {
    int nc = 1 << (12 - l), s = 1 << (l - 1);
    for (int c = wv; c < nc; c += 16)
      wave_combine(&G[(Gof[l-1]+2*c)*64], &G[(Gof[l-1]+2*c+1)*64], &G[(Gof[l]+c)*64],
                   (2*c+1)*s - 1, (2*c+2)*s - 1, lane, t, sep, dv, al, bl);
    __syncthreads();
  }
  if (tid < 64) R[Rof[12]*64 + tid] = G[Gof[12]*64 + tid];
  __syncthreads();
  for (int l = 11; l >= 7; --l) {
    int nL = 1 << (12 - l);
    for (int p = wv; p < nL; p += 16) {
      float* Ov = &R[(Rof[l]+p)*64];
      if (p == 0)        Ov[lane] = G[Gof[l]*64 + lane];
      else if (p & 1)    Ov[lane] = R[(Rof[l+1] + ((p-1)>>1))*64 + lane];
      else wave_combine(&R[(Rof[l+1] + (p>>1) - 1)*64], &G[(Gof[l]+p)*64], Ov,
                        p*(1<<l) - 1, (p+1)*(1<<l) - 1, lane, t, sep, dv, al, bl);
    }
    __syncthreads();
  }
  for (int k = wv; k < 32; k += 16) s7[k*64 + lane] = R[(31+k)*64 + lane];
}

// ---------------- K4: subtree downsweep -> xs + fused stats_part ----------
__global__ __launch_bounds__(1024) void k_down(const float* __restrict__ xcat,
    const float* __restrict__ t, const int* __restrict__ sep, const int* __restrict__ dv,
    const float* __restrict__ ap, const float* __restrict__ bp,
    const float* __restrict__ s7, float* __restrict__ xs,
    float* __restrict__ part1){
  __shared__ float G[254*64];
  __shared__ float R[255*64];
  __shared__ float bl[64*64];
  __shared__ float al[64];
  __shared__ float s7p[64];
  int b = blockIdx.x, tid = threadIdx.x, lane = tid & 63, wv = tid >> 6;
  for (int i = tid; i < 4096; i += 1024) bl[i] = bp[i];
  if (tid < 64) al[tid] = ap[tid];
  if (tid < 64) R[tid] = s7[b*64 + tid];
  if (tid >= 64 && tid < 128) s7p[tid-64] = (b > 0) ? s7[(b-1)*64 + (tid-64)] : 0.f;
  for (int k = wv; k < 128; k += 16) G[k*64 + lane] = xcat[(NN-1 - (128*b + k))*DD + lane];
  __syncthreads();
  const int Gof[7] = {0,128,192,224,240,248,252};
  const int Rof[8] = {127,63,31,15,7,3,1,0};
  for (int L = 1; L <= 6; ++L) {
    int nc = 128 >> L, s = 1 << (L-1);
    for (int c = wv; c < nc; c += 16)
      wave_combine(&G[(Gof[L-1]+2*c)*64], &G[(Gof[L-1]+2*c+1)*64], &G[(Gof[L]+c)*64],
                   128*b + (2*c+1)*s - 1, 128*b + (2*c+2)*s - 1, lane, t, sep, dv, al, bl);
    __syncthreads();
  }
  for (int L = 6; L >= 0; --L) {
    int nL = 1 << (7 - L);
    for (int p = wv; p < nL; p += 16) {
      float* Ov = &R[(Rof[L]+p)*64];
      int j = b*nL + p;
      if (j == 0)        Ov[lane] = G[Gof[L]*64 + lane];
      else if (p & 1)    Ov[lane] = R[(Rof[L+1] + ((p-1)>>1))*64 + lane];
      else {
        const float* Xv = (p == 0) ? s7p : &R[(Rof[L+1] + (p>>1) - 1)*64];
        wave_combine(Xv, &G[(Gof[L]+p)*64], Ov, j*(1<<L) - 1, (j+1)*(1<<L) - 1,
                     lane, t, sep, dv, al, bl);
      }
    }
    __syncthreads();
  }
  float a = 0.f, q = 0.f;
  for (int p = wv; p < 128; p += 16) {
    float v = R[(127+p)*64 + lane];
    xs[(NN-1 - (128*b + p))*DD + lane] = v;
    a += v; q = fmaf(v, v, q);
  }
  float* sc1 = G;           // G dead after last combine level
  float* sc2 = G + 1024;
  sc1[wv*64 + lane] = a; sc2[wv*64 + lane] = q;
  __syncthreads();
  if (tid < 64) {
    float A = 0.f, Q = 0.f;
    #pragma unroll
    for (int w = 0; w < 16; ++w) { A += sc1[w*64 + tid]; Q += sc2[w*64 + tid]; }
    part1[(b*2+0)*64 + tid] = A;
    part1[(b*2+1)*64 + tid] = Q;
  }
}

__global__ __launch_bounds__(256) void k_stats_fin(const float* __restrict__ part,
                                                   float* __restrict__ mu,
                                                   float* __restrict__ rs){
  __shared__ float s1[256], s2[256];
  int tid = threadIdx.x, d = tid & 63, p = tid >> 6;
  float a = 0.f, q = 0.f;
  #pragma unroll 8
  for (int i = p; i < 256; i += 4) {
    a += part[(i*2+0)*64 + d];
    q += part[(i*2+1)*64 + d];
  }
  s1[tid] = a; s2[tid] = q;
  __syncthreads();
  if (tid < 64) {
    float S = s1[tid]+s1[tid+64]+s1[tid+128]+s1[tid+192];
    float Q = s2[tid]+s2[tid+64]+s2[tid+128]+s2[tid+192];
    float m = S/(float)NN;
    float var = fmaxf(Q/(float)NN - m*m, 0.f);
    mu[tid] = m; rs[tid] = rsqrtf(var + 1e-6f);
  }
}

// ---------------- K6: FFN with residual + fused stats ---------------------
__global__ __launch_bounds__(256) void k_ffn(const float* __restrict__ xs,
    const float* __restrict__ xcat, const float* __restrict__ part1,
    const float* __restrict__ w1, const float* __restrict__ b1,
    const float* __restrict__ w2, const float* __restrict__ b2,
    float* __restrict__ xnew, float* __restrict__ part2){
  __shared__ float xln[16*64];
  __shared__ float Hl[16*HH];
  __shared__ float s1[256], s2[256];
  __shared__ float mu_s[64], rs_s[64];
  int b = blockIdx.x, tid = threadIdx.x;
  int n0 = b*16;
  {
    int d = tid & 63, p = tid >> 6;
    float a = 0.f, q = 0.f;
    #pragma unroll
    for (int i = p; i < 32; i += 4) {
      a += part1[(i*2+0)*64 + d];
      q += part1[(i*2+1)*64 + d];
    }
    s1[tid] = a; s2[tid] = q;
    __syncthreads();
    if (tid < 64) {
      float S = s1[tid]+s1[tid+64]+s1[tid+128]+s1[tid+192];
      float Q = s2[tid]+s2[tid+64]+s2[tid+128]+s2[tid+192];
      float m = S/(float)NN;
      float var = fmaxf(Q/(float)NN - m*m, 0.f);
      mu_s[tid] = m; rs_s[tid] = rsqrtf(var + 1e-6f);
    }
    __syncthreads();
  }
  for (int idx = tid; idx < 1024; idx += 256) {
    int i = idx >> 6, d = idx & 63;
    xln[idx] = (xs[(n0+i)*DD + d] - mu_s[d]) * rs_s[d];
  }
  float w1c[64];
  #pragma unroll
  for (int d = 0; d < 64; ++d) w1c[d] = w1[d*HH + tid];
  float bb1 = b1[tid];
  __syncthreads();
  #pragma unroll 2
  for (int i = 0; i < 16; ++i) {
    float acc = bb1;
    #pragma unroll
    for (int d = 0; d < 64; ++d) acc = fmaf(xln[i*64 + d], w1c[d], acc);
    Hl[i*HH + tid] = fmaxf(acc, 0.f);
  }
  __syncthreads();
  int e = tid & 63, ig = tid >> 6;
  float a2 = 0.f, q2 = 0.f;               // fused stats_part2 accumulators
  for (int k = 0; k < 4; ++k) {
    int i = ig + 4*k;
    float acc = b2[e];
    #pragma unroll 8
    for (int h = 0; h < HH; ++h) acc = fmaf(Hl[i*HH + h], w2[h*DD + e], acc);
    int n = n0 + i;
    float v = acc + xcat[n*DD + e];
    xnew[n*DD + e] = v;
    a2 += v; q2 = fmaf(v, v, q2);
  }
  s1[tid] = a2; s2[tid] = q2;
  __syncthreads();
  if (tid < 64) {
    part2[(b*2+0)*64 + tid] = s1[tid] + s1[tid+64] + s1[tid+128] + s1[tid+192];
    part2[(b*2+1)*64 + tid] = s2[tid] + s2[tid+64] + s2[tid+128] + s2[tid+192];
  }
}

// ---------------- K8: logits + log_softmax + gt-select --------------------
// Cached loads (r19) + e1 prefetch fenced with sched_barrier(0). Unlike
// round 12's KEEP4 ("+v" reads forced vmcnt(0) before the reduce), the
// sched_barrier is a pure compile-time ordering fence: the waitcnt before
// the max covers only e0 (FIFO vmcnt(8)), e1's loads stay in flight through
// the reduce/branch and drain at first use in the copy path.
#define FMA4(Z,W) do { Z.x=fmaf(xv,W.x,Z.x); Z.y=fmaf(xv,W.y,Z.y); \
                       Z.z=fmaf(xv,W.z,Z.z); Z.w=fmaf(xv,W.w,Z.w); } while(0)
#define MAX4(M,V) M = fmaxf(M, fmaxf(fmaxf(V.x,V.y), fmaxf(V.z,V.w)))
__global__ __launch_bounds__(256)
__attribute__((amdgpu_waves_per_eu(2, 8)))
void k_est(const float* __restrict__ xnew,
    const float* __restrict__ mu, const float* __restrict__ rs,
    const float* __restrict__ outw, const float* __restrict__ esti,
    float* __restrict__ dout){
  __shared__ float xl[64];
  __shared__ float r4a[4], r4b[4], r4c[4];
  int n = blockIdx.x, tid = threadIdx.x, lane = tid & 63, wv = tid >> 6;
  const f4* e0 = (const f4*)(esti + (size_t)n*VV);
  const f4* e1 = (const f4*)(esti + NVv + (size_t)n*VV);
  f4* o0 = (f4*)(dout + (size_t)NN*DD + (size_t)n*VV);
  f4* o1 = (f4*)(dout + (size_t)NN*DD + NVv + (size_t)n*VV);
  if (tid < 64) xl[tid] = (xnew[n*DD + tid] - mu[tid]) * rs[tid];
  f4 a0 = e0[tid],      a1 = e0[tid+256],  a2 = e0[tid+512],  a3 = e0[tid+768],
     a4 = e0[tid+1024], a5 = e0[tid+1280], a6 = e0[tid+1536], a7 = e0[tid+1792];
  f4 b0 = e1[tid],      b1 = e1[tid+256],  b2 = e1[tid+512],  b3 = e1[tid+768],
     b4 = e1[tid+1024], b5 = e1[tid+1280], b6 = e1[tid+1536], b7 = e1[tid+1792];
  __builtin_amdgcn_sched_barrier(0);   // pin load issue order; no value reads
  float mx = -1e30f;
  MAX4(mx,a0); MAX4(mx,a1); MAX4(mx,a2); MAX4(mx,a3);
  MAX4(mx,a4); MAX4(mx,a5); MAX4(mx,a6); MAX4(mx,a7);
  #pragma unroll
  for (int o = 32; o; o >>= 1) mx = fmaxf(mx, __shfl_xor(mx, o, 64));
  if (lane == 0) r4a[wv] = mx;
  __syncthreads();
  float m0 = fmaxf(fmaxf(r4a[0], r4a[1]), fmaxf(r4a[2], r4a[3]));
  if (m0 > 3.5f) {   // gt row: all 16 rows' data already in flight/regs
    ntstore(o0+tid,      a0); ntstore(o0+tid+256,  a1);
    ntstore(o0+tid+512,  a2); ntstore(o0+tid+768,  a3);
    ntstore(o0+tid+1024, a4); ntstore(o0+tid+1280, a5);
    ntstore(o0+tid+1536, a6); ntstore(o0+tid+1792, a7);
    ntstore(o1+tid,      b0); ntstore(o1+tid+256,  b1);
    ntstore(o1+tid+512,  b2); ntstore(o1+tid+768,  b3);
    ntstore(o1+tid+1024, b4); ntstore(o1+tid+1280, b5);
    ntstore(o1+tid+1536, b6); ntstore(o1+tid+1792, b7);
    return;
  }
  // compute row: o1 = e0 (frees a*/b*), then GEMV in two 4-f4 chunks
  ntstore(o1+tid,      a0); ntstore(o1+tid+256,  a1);
  ntstore(o1+tid+512,  a2); ntstore(o1+tid+768,  a3);
  ntstore(o1+tid+1024, a4); ntstore(o1+tid+1280, a5);
  ntstore(o1+tid+1536, a6); ntstore(o1+tid+1792, a7);
  f4 z00 = {0,0,0,0}, z01 = {0,0,0,0}, z02 = {0,0,0,0}, z03 = {0,0,0,0};
  for (int d = 0; d < 64; ++d) {
    float xv = xl[d];
    const f4* wr = (const f4*)(outw + (size_t)d*VV) + tid;
    f4 w0 = wr[0], w1 = wr[256], w2 = wr[512], w3 = wr[768];
    FMA4(z00,w0); FMA4(z01,w1); FMA4(z02,w2); FMA4(z03,w3);
  }
  f4 z10 = {0,0,0,0}, z11 = {0,0,0,0}, z12 = {0,0,0,0}, z13 = {0,0,0,0};
  for (int d = 0; d < 64; ++d) {
    float xv = xl[d];
    const f4* wr = (const f4*)(outw + (size_t)d*VV) + tid + 1024;
    f4 w0 = wr[0], w1 = wr[256], w2 = wr[512], w3 = wr[768];
    FMA4(z10,w0); FMA4(z11,w1); FMA4(z12,w2); FMA4(z13,w3);
  }
  float zmax = -1e30f;
  MAX4(zmax,z00); MAX4(zmax,z01); MAX4(zmax,z02); MAX4(zmax,z03);
  MAX4(zmax,z10); MAX4(zmax,z11); MAX4(zmax,z12); MAX4(zmax,z13);
  #pragma unroll
  for (int o = 32; o; o >>= 1) zmax = fmaxf(zmax, __shfl_xor(zmax, o, 64));
  if (lane == 0) r4b[wv] = zmax;
  __syncthreads();
  zmax = fmaxf(fmaxf(r4b[0], r4b[1]), fmaxf(r4b[2], r4b[3]));
  float s = 0.f;
  #define SUM4(V) s += expf(V.x - zmax) + expf(V.y - zmax) + expf(V.z - zmax) + expf(V.w - zmax)
  SUM4(z00); SUM4(z01); SUM4(z02); SUM4(z03);
  SUM4(z10); SUM4(z11); SUM4(z12); SUM4(z13);
  #undef SUM4
  #pragma unroll
  for (int o = 32; o; o >>= 1) s += __shfl_xor(s, o, 64);
  if (lane == 0) r4c[wv] = s;
  __syncthreads();
  float lse = zmax + logf(r4c[0] + r4c[1] + r4c[2] + r4c[3]);
  #define STO(Z,OFF) do { f4 v=Z; v.x-=lse; v.y-=lse; v.z-=lse; v.w-=lse; ntstore(o0+(OFF), v); } while(0)
  STO(z00, tid);        STO(z01, tid + 256);  STO(z02, tid + 512);  STO(z03, tid + 768);
  STO(z10, tid + 1024); STO(z11, tid + 1280); STO(z12, tid + 1536); STO(z13, tid + 1792);
  #undef STO
}

// ---------------- launch ----------------
extern "C" void kernel_launch(void* const* d_in, const int* in_sizes, int n_in,
                              void* d_out, int out_size, void* d_ws, size_t ws_size,
                              hipStream_t stream) {
  const float* xcat = (const float*)d_in[0];
  const float* esti = (const float*)d_in[1];
  const float* outw = (const float*)d_in[2];
  const float* delta= (const float*)d_in[3];
  const float* ap   = (const float*)d_in[4];
  const float* bp   = (const float*)d_in[5];
  const float* w1   = (const float*)d_in[6];
  const float* b1   = (const float*)d_in[7];
  const float* w2   = (const float*)d_in[8];
  const float* b2   = (const float*)d_in[9];
  const int* xsep   = (const int*)d_in[10];
  const int* xdiv   = (const int*)d_in[11];
  const int* seedp  = (const int*)d_in[12];
  float* out = (float*)d_out;

  char* ws = (char*)d_ws;
  float* t     = (float*)(ws);                      // 4096 f
  int*   dv    = (int*)  (ws + 16384);              // 4096 i
  float* g7    = (float*)(ws + 32768);              // 2048 f
  float* s7    = (float*)(ws + 40960);              // 2048 f
  float* xs    = (float*)(ws + 49152);              // 262144 f (1 MB)
  float* mu2   = (float*)(ws + 49152 + 1048576);
  float* rs2   = mu2 + 64;
  float* part1 = (float*)(ws + 49152 + 1048576 + 4096);           // 32*2*64 f
  float* part2 = (float*)(ws + 49152 + 1048576 + 4096 + 131072);  // 128 KB

  hipLaunchKernelGGL(k_pre,        dim3(65),   dim3(256),  0, stream, xcat, delta, xdiv, seedp, t, dv);
  hipLaunchKernelGGL(k_up,         dim3(32),   dim3(1024), 0, stream, xcat, t, xsep, dv, ap, bp, g7);
  hipLaunchKernelGGL(k_mid,        dim3(1),    dim3(1024), 0, stream, t, xsep, dv, ap, bp, g7, s7);
  hipLaunchKernelGGL(k_down,       dim3(32),   dim3(1024), 0, stream, xcat, t, xsep, dv, ap, bp, s7, xs, part1);
  hipLaunchKernelGGL(k_ffn,        dim3(256),  dim3(256),  0, stream, xs, xcat, part1, w1, b1, w2, b2, out, part2);
  hipLaunchKernelGGL(k_stats_fin,  dim3(1),    dim3(256),  0, stream, part2, mu2, rs2);
  hipLaunchKernelGGL(k_est,        dim3(NN),   dim3(256),  0, stream, out, mu2, rs2, outw, esti, out);
}

// Round 21
// 243.003 us; speedup vs baseline: 1.0789x; 1.0789x over previous
//
#include <hip/hip_runtime.h>
#include <stdint.h>

#define NN 4096
#define DD 64
#define HH 256
#define VV 8192
#define NVv ((size_t)NN*(size_t)VV)

typedef float f4 __attribute__((ext_vector_type(4)));
__device__ __forceinline__ void ntstore(f4* p, f4 v){ __builtin_nontemporal_store(v, p); }

// ---------------- threefry2x32 (exact JAX replication) ----------------
__device__ __forceinline__ uint32_t rotl32(uint32_t v, int r){ return (v<<r)|(v>>(32-r)); }
#define TF_ROUND(r) do { x0 += x1; x1 = rotl32(x1, r); x1 ^= x0; } while(0)
__device__ __forceinline__ void threefry2x32(uint32_t k0, uint32_t k1,
                                             uint32_t c0, uint32_t c1,
                                             uint32_t& o0, uint32_t& o1){
  uint32_t ks2 = k0 ^ k1 ^ 0x1BD11BDAu;
  uint32_t x0 = c0 + k0, x1 = c1 + k1;
  TF_ROUND(13); TF_ROUND(15); TF_ROUND(26); TF_ROUND(6);
  x0 += k1;  x1 += ks2 + 1u;
  TF_ROUND(17); TF_ROUND(29); TF_ROUND(16); TF_ROUND(24);
  x0 += ks2; x1 += k0 + 2u;
  TF_ROUND(13); TF_ROUND(15); TF_ROUND(26); TF_ROUND(6);
  x0 += k0;  x1 += k1 + 3u;
  TF_ROUND(17); TF_ROUND(29); TF_ROUND(16); TF_ROUND(24);
  x0 += k1;  x1 += ks2 + 4u;
  TF_ROUND(13); TF_ROUND(15); TF_ROUND(26); TF_ROUND(6);
  x0 += ks2; x1 += k0 + 5u;
  o0 = x0; o1 = x1;
}

// ---------------- K1: fused t = log_sigmoid(xcat@delta) + RNG/cumsum -------
__global__ __launch_bounds__(256) void k_pre(const float* __restrict__ xcat,
                                             const float* __restrict__ delta,
                                             const int* __restrict__ xdiv,
                                             const int* __restrict__ seedp,
                                             float* __restrict__ t,
                                             int* __restrict__ dv){
  __shared__ float xr[64*65];
  __shared__ float dl[64];
  __shared__ int   md[NN];
  __shared__ int   ps[256];
  int tid = threadIdx.x;
  if (blockIdx.x < 64) {
    int b = blockIdx.x;
    if (tid < 64) dl[tid] = delta[tid];
    const float4* src = (const float4*)(xcat + (size_t)b*4096);
    for (int i = tid; i < 1024; i += 256) {
      float4 v = src[i];
      int r = i >> 4, c = (i & 15)*4;
      float* p = &xr[r*65 + c];
      p[0]=v.x; p[1]=v.y; p[2]=v.z; p[3]=v.w;
    }
    __syncthreads();
    if (tid < 64) {
      float acc = 0.f;
      #pragma unroll 16
      for (int d = 0; d < 64; ++d) acc = fmaf(xr[tid*65 + d], dl[d], acc);
      t[b*64 + tid] = fminf(acc, 0.f) - log1pf(expf(-fabsf(acc)));
    }
    return;
  }
  // block 64: RNG + cumsum
  uint32_t seed = (uint32_t)seedp[0];
  uint32_t sk0, sk1;
  threefry2x32(0u, seed, 0u, 1u, sk0, sk1);    // foldlike split -> subkey
  for (int i = tid; i < NN; i += 256) {
    uint32_t o0, o1; threefry2x32(sk0, sk1, 0u, (uint32_t)i, o0, o1);
    uint32_t bits = o0 ^ o1;                   // partitionable 32-bit bits
    float u = __uint_as_float((bits>>9)|0x3f800000u) - 1.0f;
    md[i] = (u > 0.1f) ? xdiv[i] : 0;
  }
  __syncthreads();
  int base = tid*16, s = 0;
  #pragma unroll
  for (int k=0;k<16;k++){ s += md[base+k]; md[base+k] = s; }
  ps[tid] = s;
  __syncthreads();
  if (tid < 64) {                              // wave-parallel exclusive scan
    int a0 = ps[4*tid], a1 = ps[4*tid+1], a2 = ps[4*tid+2], a3 = ps[4*tid+3];
    int s4 = a0+a1+a2+a3;
    int v = s4;
    #pragma unroll
    for (int o = 1; o < 64; o <<= 1) { int u = __shfl_up(v, o, 64); if (tid >= o) v += u; }
    int e = v - s4;
    ps[4*tid] = e; ps[4*tid+1] = e+a0; ps[4*tid+2] = e+a0+a1; ps[4*tid+3] = e+a0+a1+a2;
  }
  __syncthreads();
  int off = ps[tid];
  #pragma unroll
  for (int k=0;k<16;k++) dv[base+k] = md[base+k] + off;
}

// ---------------- wave-level combine (f-order): O = Y + m * (X*exp(dt*a)) @ B
__device__ __forceinline__ void wave_combine(const float* __restrict__ Xv,
                                             const float* __restrict__ Yv,
                                             float* __restrict__ Ov,
                                             int bidx, int cidx, int lane,
                                             const float* __restrict__ t,
                                             const int* __restrict__ sep,
                                             const int* __restrict__ dv,
                                             const float* __restrict__ al,
                                             const float* __restrict__ bl){
  int eb = (NN-1) - bidx, ec = (NN-1) - cidx;   // e-order indices
  float acc = Yv[lane];
  if (sep[eb] == sep[ec] && dv[eb] == dv[ec]) {
    float dt = t[ec] - t[eb];
    float w = Xv[lane] * expf(dt * al[lane]);
    #pragma unroll 16
    for (int d = 0; d < 64; ++d)
      acc = fmaf(__shfl(w, d, 64), bl[d*64 + lane], acc);
  }
  Ov[lane] = acc;
}

// ---------------- K2: subtree upsweep (levels 1..7) -> g7 ----------------
__global__ __launch_bounds__(1024) void k_up(const float* __restrict__ xcat,
    const float* __restrict__ t, const int* __restrict__ sep, const int* __restrict__ dv,
    const float* __restrict__ ap, const float* __restrict__ bp, float* __restrict__ g7){
  __shared__ float G[255*64];
  __shared__ float bl[64*64];
  __shared__ float al[64];
  int b = blockIdx.x, tid = threadIdx.x, lane = tid & 63, wv = tid >> 6;
  for (int i = tid; i < 4096; i += 1024) bl[i] = bp[i];
  if (tid < 64) al[tid] = ap[tid];
  for (int k = wv; k < 128; k += 16) G[k*64 + lane] = xcat[(NN-1 - (128*b + k))*DD + lane];
  __syncthreads();
  const int Gof[8] = {0,128,192,224,240,248,252,254};
  for (int L = 1; L <= 7; ++L) {
    int nc = 128 >> L, s = 1 << (L-1);
    for (int c = wv; c < nc; c += 16)
      wave_combine(&G[(Gof[L-1]+2*c)*64], &G[(Gof[L-1]+2*c+1)*64], &G[(Gof[L]+c)*64],
                   128*b + (2*c+1)*s - 1, 128*b + (2*c+2)*s - 1, lane, t, sep, dv, al, bl);
    __syncthreads();
  }
  if (tid < 64) g7[b*64 + tid] = G[254*64 + tid];
}

// ---------------- K3: middle levels 8..12 up + down -> scanned_7 ----------
__global__ __launch_bounds__(1024) void k_mid(const float* __restrict__ t,
    const int* __restrict__ sep, const int* __restrict__ dv,
    const float* __restrict__ ap, const float* __restrict__ bp,
    const float* __restrict__ g7, float* __restrict__ s7){
  __shared__ float G[63*64];
  __shared__ float R[63*64];
  __shared__ float bl[64*64];
  __shared__ float al[64];
  int tid = threadIdx.x, lane = tid & 63, wv = tid >> 6;
  for (int i = tid; i < 4096; i += 1024) bl[i] = bp[i];
  if (tid < 64) al[tid] = ap[tid];
  for (int k = wv; k < 32; k += 16) G[k*64 + lane] = g7[k*64 + lane];
  __syncthreads();
  const int Gof[13] = {0,0,0,0,0,0,0, 0,32,48,56,60,62};
  const int Rof[13] = {0,0,0,0,0,0,0, 31,15,7,3,1,0};
  for (int l = 8; l <= 12; ++l) {
    int nc = 1 << (12 - l), s = 1 << (l - 1);
    for (int c = wv; c < nc; c += 16)
      wave_combine(&G[(Gof[l-1]+2*c)*64], &G[(Gof[l-1]+2*c+1)*64], &G[(Gof[l]+c)*64],
                   (2*c+1)*s - 1, (2*c+2)*s - 1, lane, t, sep, dv, al, bl);
    __syncthreads();
  }
  if (tid < 64) R[Rof[12]*64 + tid] = G[Gof[12]*64 + tid];
  __syncthreads();
  for (int l = 11; l >= 7; --l) {
    int nL = 1 << (12 - l);
    for (int p = wv; p < nL; p += 16) {
      float* Ov = &R[(Rof[l]+p)*64];
      if (p == 0)        Ov[lane] = G[Gof[l]*64 + lane];
      else if (p & 1)    Ov[lane] = R[(Rof[l+1] + ((p-1)>>1))*64 + lane];
      else wave_combine(&R[(Rof[l+1] + (p>>1) - 1)*64], &G[(Gof[l]+p)*64], Ov,
                        p*(1<<l) - 1, (p+1)*(1<<l) - 1, lane, t, sep, dv, al, bl);
    }
    __syncthreads();
  }
  for (int k = wv; k < 32; k += 16) s7[k*64 + lane] = R[(31+k)*64 + lane];
}

// ---------------- K4: subtree downsweep -> xs + fused stats_part ----------
__global__ __launch_bounds__(1024) void k_down(const float* __restrict__ xcat,
    const float* __restrict__ t, const int* __restrict__ sep, const int* __restrict__ dv,
    const float* __restrict__ ap, const float* __restrict__ bp,
    const float* __restrict__ s7, float* __restrict__ xs,
    float* __restrict__ part1){
  __shared__ float G[254*64];
  __shared__ float R[255*64];
  __shared__ float bl[64*64];
  __shared__ float al[64];
  __shared__ float s7p[64];
  int b = blockIdx.x, tid = threadIdx.x, lane = tid & 63, wv = tid >> 6;
  for (int i = tid; i < 4096; i += 1024) bl[i] = bp[i];
  if (tid < 64) al[tid] = ap[tid];
  if (tid < 64) R[tid] = s7[b*64 + tid];
  if (tid >= 64 && tid < 128) s7p[tid-64] = (b > 0) ? s7[(b-1)*64 + (tid-64)] : 0.f;
  for (int k = wv; k < 128; k += 16) G[k*64 + lane] = xcat[(NN-1 - (128*b + k))*DD + lane];
  __syncthreads();
  const int Gof[7] = {0,128,192,224,240,248,252};
  const int Rof[8] = {127,63,31,15,7,3,1,0};
  for (int L = 1; L <= 6; ++L) {
    int nc = 128 >> L, s = 1 << (L-1);
    for (int c = wv; c < nc; c += 16)
      wave_combine(&G[(Gof[L-1]+2*c)*64], &G[(Gof[L-1]+2*c+1)*64], &G[(Gof[L]+c)*64],
                   128*b + (2*c+1)*s - 1, 128*b + (2*c+2)*s - 1, lane, t, sep, dv, al, bl);
    __syncthreads();
  }
  for (int L = 6; L >= 0; --L) {
    int nL = 1 << (7 - L);
    for (int p = wv; p < nL; p += 16) {
      float* Ov = &R[(Rof[L]+p)*64];
      int j = b*nL + p;
      if (j == 0)        Ov[lane] = G[Gof[L]*64 + lane];
      else if (p & 1)    Ov[lane] = R[(Rof[L+1] + ((p-1)>>1))*64 + lane];
      else {
        const float* Xv = (p == 0) ? s7p : &R[(Rof[L+1] + (p>>1) - 1)*64];
        wave_combine(Xv, &G[(Gof[L]+p)*64], Ov, j*(1<<L) - 1, (j+1)*(1<<L) - 1,
                     lane, t, sep, dv, al, bl);
      }
    }
    __syncthreads();
  }
  float a = 0.f, q = 0.f;
  for (int p = wv; p < 128; p += 16) {
    float v = R[(127+p)*64 + lane];
    xs[(NN-1 - (128*b + p))*DD + lane] = v;
    a += v; q = fmaf(v, v, q);
  }
  float* sc1 = G;           // G dead after last combine level
  float* sc2 = G + 1024;
  sc1[wv*64 + lane] = a; sc2[wv*64 + lane] = q;
  __syncthreads();
  if (tid < 64) {
    float A = 0.f, Q = 0.f;
    #pragma unroll
    for (int w = 0; w < 16; ++w) { A += sc1[w*64 + tid]; Q += sc2[w*64 + tid]; }
    part1[(b*2+0)*64 + tid] = A;
    part1[(b*2+1)*64 + tid] = Q;
  }
}

__global__ __launch_bounds__(256) void k_stats_fin(const float* __restrict__ part,
                                                   float* __restrict__ mu,
                                                   float* __restrict__ rs){
  __shared__ float s1[256], s2[256];
  int tid = threadIdx.x, d = tid & 63, p = tid >> 6;
  float a = 0.f, q = 0.f;
  #pragma unroll 8
  for (int i = p; i < 256; i += 4) {
    a += part[(i*2+0)*64 + d];
    q += part[(i*2+1)*64 + d];
  }
  s1[tid] = a; s2[tid] = q;
  __syncthreads();
  if (tid < 64) {
    float S = s1[tid]+s1[tid+64]+s1[tid+128]+s1[tid+192];
    float Q = s2[tid]+s2[tid+64]+s2[tid+128]+s2[tid+192];
    float m = S/(float)NN;
    float var = fmaxf(Q/(float)NN - m*m, 0.f);
    mu[tid] = m; rs[tid] = rsqrtf(var + 1e-6f);
  }
}

// ---------------- K6: FFN with residual + fused stats ---------------------
__global__ __launch_bounds__(256) void k_ffn(const float* __restrict__ xs,
    const float* __restrict__ xcat, const float* __restrict__ part1,
    const float* __restrict__ w1, const float* __restrict__ b1,
    const float* __restrict__ w2, const float* __restrict__ b2,
    float* __restrict__ xnew, float* __restrict__ part2){
  __shared__ float xln[16*64];
  __shared__ float Hl[16*HH];
  __shared__ float s1[256], s2[256];
  __shared__ float mu_s[64], rs_s[64];
  int b = blockIdx.x, tid = threadIdx.x;
  int n0 = b*16;
  {
    int d = tid & 63, p = tid >> 6;
    float a = 0.f, q = 0.f;
    #pragma unroll
    for (int i = p; i < 32; i += 4) {
      a += part1[(i*2+0)*64 + d];
      q += part1[(i*2+1)*64 + d];
    }
    s1[tid] = a; s2[tid] = q;
    __syncthreads();
    if (tid < 64) {
      float S = s1[tid]+s1[tid+64]+s1[tid+128]+s1[tid+192];
      float Q = s2[tid]+s2[tid+64]+s2[tid+128]+s2[tid+192];
      float m = S/(float)NN;
      float var = fmaxf(Q/(float)NN - m*m, 0.f);
      mu_s[tid] = m; rs_s[tid] = rsqrtf(var + 1e-6f);
    }
    __syncthreads();
  }
  for (int idx = tid; idx < 1024; idx += 256) {
    int i = idx >> 6, d = idx & 63;
    xln[idx] = (xs[(n0+i)*DD + d] - mu_s[d]) * rs_s[d];
  }
  float w1c[64];
  #pragma unroll
  for (int d = 0; d < 64; ++d) w1c[d] = w1[d*HH + tid];
  float bb1 = b1[tid];
  __syncthreads();
  #pragma unroll 2
  for (int i = 0; i < 16; ++i) {
    float acc = bb1;
    #pragma unroll
    for (int d = 0; d < 64; ++d) acc = fmaf(xln[i*64 + d], w1c[d], acc);
    Hl[i*HH + tid] = fmaxf(acc, 0.f);
  }
  __syncthreads();
  int e = tid & 63, ig = tid >> 6;
  float a2 = 0.f, q2 = 0.f;               // fused stats_part2 accumulators
  for (int k = 0; k < 4; ++k) {
    int i = ig + 4*k;
    float acc = b2[e];
    #pragma unroll 8
    for (int h = 0; h < HH; ++h) acc = fmaf(Hl[i*HH + h], w2[h*DD + e], acc);
    int n = n0 + i;
    float v = acc + xcat[n*DD + e];
    xnew[n*DD + e] = v;
    a2 += v; q2 = fmaf(v, v, q2);
  }
  s1[tid] = a2; s2[tid] = q2;
  __syncthreads();
  if (tid < 64) {
    part2[(b*2+0)*64 + tid] = s1[tid] + s1[tid+64] + s1[tid+128] + s1[tid+192];
    part2[(b*2+1)*64 + tid] = s2[tid] + s2[tid+64] + s2[tid+128] + s2[tid+192];
  }
}

// ---------------- K8: logits + log_softmax + gt-select --------------------
// Round-19 form (best: 246.3 us): cached loads for esti (L3-resident across
// graph replays, protected by nt stores), nt stores for o0/o1, e1 demand-
// loaded in the copy branch. e1 prefetch refuted twice (r12 vmcnt poison,
// r20 register pressure: VGPR 72, occ -6pp, +16 us).
#define FMA4(Z,W) do { Z.x=fmaf(xv,W.x,Z.x); Z.y=fmaf(xv,W.y,Z.y); \
                       Z.z=fmaf(xv,W.z,Z.z); Z.w=fmaf(xv,W.w,Z.w); } while(0)
#define MAX4(M,V) M = fmaxf(M, fmaxf(fmaxf(V.x,V.y), fmaxf(V.z,V.w)))
__global__ __launch_bounds__(256)
__attribute__((amdgpu_waves_per_eu(2, 8)))
void k_est(const float* __restrict__ xnew,
    const float* __restrict__ mu, const float* __restrict__ rs,
    const float* __restrict__ outw, const float* __restrict__ esti,
    float* __restrict__ dout){
  __shared__ float xl[64];
  __shared__ float r4a[4], r4b[4], r4c[4];
  int n = blockIdx.x, tid = threadIdx.x, lane = tid & 63, wv = tid >> 6;
  const f4* e0 = (const f4*)(esti + (size_t)n*VV);
  const f4* e1 = (const f4*)(esti + NVv + (size_t)n*VV);
  f4* o0 = (f4*)(dout + (size_t)NN*DD + (size_t)n*VV);
  f4* o1 = (f4*)(dout + (size_t)NN*DD + NVv + (size_t)n*VV);
  if (tid < 64) xl[tid] = (xnew[n*DD + tid] - mu[tid]) * rs[tid];
  f4 a0 = e0[tid],      a1 = e0[tid+256],  a2 = e0[tid+512],  a3 = e0[tid+768],
     a4 = e0[tid+1024], a5 = e0[tid+1280], a6 = e0[tid+1536], a7 = e0[tid+1792];
  float mx = -1e30f;
  MAX4(mx,a0); MAX4(mx,a1); MAX4(mx,a2); MAX4(mx,a3);
  MAX4(mx,a4); MAX4(mx,a5); MAX4(mx,a6); MAX4(mx,a7);
  #pragma unroll
  for (int o = 32; o; o >>= 1) mx = fmaxf(mx, __shfl_xor(mx, o, 64));
  if (lane == 0) r4a[wv] = mx;
  __syncthreads();
  float m0 = fmaxf(fmaxf(r4a[0], r4a[1]), fmaxf(r4a[2], r4a[3]));
  if (m0 > 3.5f) {   // gt row: o0 = e0 (regs), o1 = e1 (cached loads, nt stores)
    ntstore(o0+tid,      a0); ntstore(o0+tid+256,  a1);
    ntstore(o0+tid+512,  a2); ntstore(o0+tid+768,  a3);
    ntstore(o0+tid+1024, a4); ntstore(o0+tid+1280, a5);
    ntstore(o0+tid+1536, a6); ntstore(o0+tid+1792, a7);
    f4 b0 = e1[tid],      b1 = e1[tid+256],  b2 = e1[tid+512],  b3 = e1[tid+768],
       b4 = e1[tid+1024], b5 = e1[tid+1280], b6 = e1[tid+1536], b7 = e1[tid+1792];
    ntstore(o1+tid,      b0); ntstore(o1+tid+256,  b1);
    ntstore(o1+tid+512,  b2); ntstore(o1+tid+768,  b3);
    ntstore(o1+tid+1024, b4); ntstore(o1+tid+1280, b5);
    ntstore(o1+tid+1536, b6); ntstore(o1+tid+1792, b7);
    return;
  }
  // compute row: o1 = e0 (frees a*), then GEMV in two 4-f4 chunks
  ntstore(o1+tid,      a0); ntstore(o1+tid+256,  a1);
  ntstore(o1+tid+512,  a2); ntstore(o1+tid+768,  a3);
  ntstore(o1+tid+1024, a4); ntstore(o1+tid+1280, a5);
  ntstore(o1+tid+1536, a6); ntstore(o1+tid+1792, a7);
  f4 z00 = {0,0,0,0}, z01 = {0,0,0,0}, z02 = {0,0,0,0}, z03 = {0,0,0,0};
  for (int d = 0; d < 64; ++d) {
    float xv = xl[d];
    const f4* wr = (const f4*)(outw + (size_t)d*VV) + tid;
    f4 w0 = wr[0], w1 = wr[256], w2 = wr[512], w3 = wr[768];
    FMA4(z00,w0); FMA4(z01,w1); FMA4(z02,w2); FMA4(z03,w3);
  }
  f4 z10 = {0,0,0,0}, z11 = {0,0,0,0}, z12 = {0,0,0,0}, z13 = {0,0,0,0};
  for (int d = 0; d < 64; ++d) {
    float xv = xl[d];
    const f4* wr = (const f4*)(outw + (size_t)d*VV) + tid + 1024;
    f4 w0 = wr[0], w1 = wr[256], w2 = wr[512], w3 = wr[768];
    FMA4(z10,w0); FMA4(z11,w1); FMA4(z12,w2); FMA4(z13,w3);
  }
  float zmax = -1e30f;
  MAX4(zmax,z00); MAX4(zmax,z01); MAX4(zmax,z02); MAX4(zmax,z03);
  MAX4(zmax,z10); MAX4(zmax,z11); MAX4(zmax,z12); MAX4(zmax,z13);
  #pragma unroll
  for (int o = 32; o; o >>= 1) zmax = fmaxf(zmax, __shfl_xor(zmax, o, 64));
  if (lane == 0) r4b[wv] = zmax;
  __syncthreads();
  zmax = fmaxf(fmaxf(r4b[0], r4b[1]), fmaxf(r4b[2], r4b[3]));
  float s = 0.f;
  #define SUM4(V) s += expf(V.x - zmax) + expf(V.y - zmax) + expf(V.z - zmax) + expf(V.w - zmax)
  SUM4(z00); SUM4(z01); SUM4(z02); SUM4(z03);
  SUM4(z10); SUM4(z11); SUM4(z12); SUM4(z13);
  #undef SUM4
  #pragma unroll
  for (int o = 32; o; o >>= 1) s += __shfl_xor(s, o, 64);
  if (lane == 0) r4c[wv] = s;
  __syncthreads();
  float lse = zmax + logf(r4c[0] + r4c[1] + r4c[2] + r4c[3]);
  #define STO(Z,OFF) do { f4 v=Z; v.x-=lse; v.y-=lse; v.z-=lse; v.w-=lse; ntstore(o0+(OFF), v); } while(0)
  STO(z00, tid);        STO(z01, tid + 256);  STO(z02, tid + 512);  STO(z03, tid + 768);
  STO(z10, tid + 1024); STO(z11, tid + 1280); STO(z12, tid + 1536); STO(z13, tid + 1792);
  #undef STO
}

// ---------------- launch ----------------
extern "C" void kernel_launch(void* const* d_in, const int* in_sizes, int n_in,
                              void* d_out, int out_size, void* d_ws, size_t ws_size,
                              hipStream_t stream) {
  const float* xcat = (const float*)d_in[0];
  const float* esti = (const float*)d_in[1];
  const float* outw = (const float*)d_in[2];
  const float* delta= (const float*)d_in[3];
  const float* ap   = (const float*)d_in[4];
  const float* bp   = (const float*)d_in[5];
  const float* w1   = (const float*)d_in[6];
  const float* b1   = (const float*)d_in[7];
  const float* w2   = (const float*)d_in[8];
  const float* b2   = (const float*)d_in[9];
  const int* xsep   = (const int*)d_in[10];
  const int* xdiv   = (const int*)d_in[11];
  const int* seedp  = (const int*)d_in[12];
  float* out = (float*)d_out;

  char* ws = (char*)d_ws;
  float* t     = (float*)(ws);                      // 4096 f
  int*   dv    = (int*)  (ws + 16384);              // 4096 i
  float* g7    = (float*)(ws + 32768);              // 2048 f
  float* s7    = (float*)(ws + 40960);              // 2048 f
  float* xs    = (float*)(ws + 49152);              // 262144 f (1 MB)
  float* mu2   = (float*)(ws + 49152 + 1048576);
  float* rs2   = mu2 + 64;
  float* part1 = (float*)(ws + 49152 + 1048576 + 4096);           // 32*2*64 f
  float* part2 = (float*)(ws + 49152 + 1048576 + 4096 + 131072);  // 128 KB

  hipLaunchKernelGGL(k_pre,        dim3(65),   dim3(256),  0, stream, xcat, delta, xdiv, seedp, t, dv);
  hipLaunchKernelGGL(k_up,         dim3(32),   dim3(1024), 0, stream, xcat, t, xsep, dv, ap, bp, g7);
  hipLaunchKernelGGL(k_mid,        dim3(1),    dim3(1024), 0, stream, t, xsep, dv, ap, bp, g7, s7);
  hipLaunchKernelGGL(k_down,       dim3(32),   dim3(1024), 0, stream, xcat, t, xsep, dv, ap, bp, s7, xs, part1);
  hipLaunchKernelGGL(k_ffn,        dim3(256),  dim3(256),  0, stream, xs, xcat, part1, w1, b1, w2, b2, out, part2);
  hipLaunchKernelGGL(k_stats_fin,  dim3(1),    dim3(256),  0, stream, part2, mu2, rs2);
  hipLaunchKernelGGL(k_est,        dim3(NN),   dim3(256),  0, stream, out, mu2, rs2, outw, esti, out);
}